// Round 10
// baseline (731.840 us; speedup 1.0000x reference)
//
#include <hip/hip_runtime.h>
#include <math.h>

#define NW 5
#define NS 5
#define BB 25            // NW*NS
#define CD 640
#define HWD 576
#define NP 2880          // NS*HWD
#define KTOP 2304        // int(2880*0.8)
#define EPSF 1e-12f

typedef __attribute__((ext_vector_type(8))) short short8;   // 8 bf16 (4 VGPRs)
typedef __attribute__((ext_vector_type(4))) float f32x4;

__device__ inline unsigned short f2bf(float x) {            // RNE float->bf16
    unsigned u = __float_as_uint(x);
    return (unsigned short)((u + 0x7fffu + ((u >> 16) & 1u)) >> 16);
}
__device__ inline float bf2f(unsigned short h) { return __uint_as_float(((unsigned)h) << 16); }

__device__ inline void gload_lds16(const void* g, void* l) {
    __builtin_amdgcn_global_load_lds(
        (const __attribute__((address_space(1))) unsigned int*)g,
        (__attribute__((address_space(3))) unsigned int*)l, 16, 0, 0);
}

// ---------------------------------------------------------------------------
// device: LDS-tiled fp32 640-GEMM tile. mode0: C=A^T B. mode1: C=A B (+add).
// Optional fp32 C and/or bf16 hi/lo H/L outputs. 64x64 tile, one (bx,by).
// ---------------------------------------------------------------------------
__device__ void dev_gemm640(const float* __restrict__ A, const float* __restrict__ B,
                            const float* __restrict__ add, float* __restrict__ C,
                            unsigned short* __restrict__ H, unsigned short* __restrict__ L,
                            int mode, int bx, int by, char* smem)
{
    float (*At)[68] = (float(*)[68])smem;            // 32x68
    float (*Bt)[64] = (float(*)[64])(smem + 8704);   // 32x64
    const int o0 = by * 64, j0 = bx * 64;
    const int t  = threadIdx.x;
    const int to = (t >> 4) * 4, tj = (t & 15) * 4;

    float acc[4][4];
#pragma unroll
    for (int r = 0; r < 4; ++r)
#pragma unroll
        for (int s = 0; s < 4; ++s) acc[r][s] = 0.f;

    for (int c0 = 0; c0 < CD; c0 += 32) {
        __syncthreads();
        {
            const int r = t >> 3, c8 = (t & 7) * 8;
            float4 b0 = *(const float4*)&B[(size_t)(c0+r)*CD + j0 + c8];
            float4 b1 = *(const float4*)&B[(size_t)(c0+r)*CD + j0 + c8 + 4];
            *(float4*)&Bt[r][c8]     = b0;
            *(float4*)&Bt[r][c8 + 4] = b1;
            if (mode == 0) {
                float4 a0 = *(const float4*)&A[(size_t)(c0+r)*CD + o0 + c8];
                float4 a1 = *(const float4*)&A[(size_t)(c0+r)*CD + o0 + c8 + 4];
                *(float4*)&At[r][c8]     = a0;
                *(float4*)&At[r][c8 + 4] = a1;
            } else {
                const int r2 = t >> 2, c82 = (t & 3) * 8;
                float4 a0 = *(const float4*)&A[(size_t)(o0+r2)*CD + c0 + c82];
                float4 a1 = *(const float4*)&A[(size_t)(o0+r2)*CD + c0 + c82 + 4];
                At[c82+0][r2] = a0.x; At[c82+1][r2] = a0.y;
                At[c82+2][r2] = a0.z; At[c82+3][r2] = a0.w;
                At[c82+4][r2] = a1.x; At[c82+5][r2] = a1.y;
                At[c82+6][r2] = a1.z; At[c82+7][r2] = a1.w;
            }
        }
        __syncthreads();
#pragma unroll
        for (int kk = 0; kk < 32; ++kk) {
            float4 av = *(const float4*)&At[kk][to];
            float4 bv = *(const float4*)&Bt[kk][tj];
            float aa[4] = {av.x, av.y, av.z, av.w};
            float bb[4] = {bv.x, bv.y, bv.z, bv.w};
#pragma unroll
            for (int r = 0; r < 4; ++r)
#pragma unroll
                for (int s = 0; s < 4; ++s)
                    acc[r][s] = fmaf(aa[r], bb[s], acc[r][s]);
        }
    }

#pragma unroll
    for (int r = 0; r < 4; ++r) {
        float v[4] = {acc[r][0], acc[r][1], acc[r][2], acc[r][3]};
        const size_t base = (size_t)(o0+to+r)*CD + j0 + tj;
        if (add != nullptr) {
            float4 ad = *(const float4*)&add[base];
            v[0] += ad.x; v[1] += ad.y; v[2] += ad.z; v[3] += ad.w;
        }
        if (C != nullptr) {
            float4 o4; o4.x = v[0]; o4.y = v[1]; o4.z = v[2]; o4.w = v[3];
            *(float4*)&C[base] = o4;
        }
        if (H != nullptr) {
            ushort4 h, l;
            h.x = f2bf(v[0]); h.y = f2bf(v[1]); h.z = f2bf(v[2]); h.w = f2bf(v[3]);
            l.x = f2bf(v[0] - bf2f(h.x)); l.y = f2bf(v[1] - bf2f(h.y));
            l.z = f2bf(v[2] - bf2f(h.z)); l.w = f2bf(v[3] - bf2f(h.w));
            *(ushort4*)&H[base] = h; *(ushort4*)&L[base] = l;
        }
    }
}

// device: 64x64 transpose + bf16 hi/lo split of one lf tile
__device__ void dev_convert(const float* __restrict__ in, unsigned short* __restrict__ Oh,
                            unsigned short* __restrict__ Ol, int b, int xidx, char* smem)
{
    float (*tile)[65] = (float(*)[65])smem;
    const int c0 = (xidx / 9) * 64;
    const int p0 = (xidx % 9) * 64;
    const int t  = threadIdx.x;
    const float* src = in + (size_t)b * CD * HWD;
#pragma unroll
    for (int it = 0; it < 4; ++it) {
        int cl = (t >> 4) + 16*it, pl = (t & 15) * 4;
        float4 v = *(const float4*)&src[(size_t)(c0+cl)*HWD + p0 + pl];
        tile[cl][pl] = v.x; tile[cl][pl+1] = v.y; tile[cl][pl+2] = v.z; tile[cl][pl+3] = v.w;
    }
    __syncthreads();
#pragma unroll
    for (int it = 0; it < 4; ++it) {
        int pl = (t >> 4) + 16*it, clb = (t & 15) * 4;
        ushort4 hv, lv;
        float x0 = tile[clb+0][pl], x1 = tile[clb+1][pl], x2 = tile[clb+2][pl], x3 = tile[clb+3][pl];
        hv.x = f2bf(x0); hv.y = f2bf(x1); hv.z = f2bf(x2); hv.w = f2bf(x3);
        lv.x = f2bf(x0 - bf2f(hv.x)); lv.y = f2bf(x1 - bf2f(hv.y));
        lv.z = f2bf(x2 - bf2f(hv.z)); lv.w = f2bf(x3 - bf2f(hv.w));
        size_t o = (size_t)(b*HWD + p0 + pl) * CD + c0 + clb;
        *(ushort4*)&Oh[o] = hv;
        *(ushort4*)&Ol[o] = lv;
    }
}

// ---------------------------------------------------------------------------
// prep_a: [0,100) M2=Wq^T Wk | [100,200) Weff=Wq*Wc+Wq | [200,210) wqtbk/bqwk
// [210,220) beff | [220] sbb | [221,2471) convert_t(lf) | [2471,2503) zeros
// ---------------------------------------------------------------------------
__global__ __launch_bounds__(256) void prep_a(
    const float* __restrict__ lf, const float* __restrict__ Wc,
    const float* __restrict__ bc, const float* __restrict__ Wq,
    const float* __restrict__ bq, const float* __restrict__ Wk,
    const float* __restrict__ bk,
    float* __restrict__ M2, float* __restrict__ Weff,
    float* __restrict__ wqtbk, float* __restrict__ bqwk, float* __restrict__ beff,
    float* __restrict__ sbb,
    unsigned short* __restrict__ lfTh, unsigned short* __restrict__ lfTl,
    float* __restrict__ cor, float* __restrict__ sumsq, float* __restrict__ rvsum,
    float* __restrict__ proto1, float* __restrict__ scal)
{
    __shared__ __align__(16) char smem[16896];
    const int blk = blockIdx.x;
    const int t = threadIdx.x;
    if (blk < 100) {
        dev_gemm640(Wq, Wk, nullptr, M2, nullptr, nullptr, 0, blk % 10, blk / 10, smem);
    } else if (blk < 200) {
        int b2 = blk - 100;
        dev_gemm640(Wq, Wc, Wq, Weff, nullptr, nullptr, 1, b2 % 10, b2 / 10, smem);
    } else if (blk < 210) {
        const int o = (blk - 200)*64 + (t >> 2);
        const int m0 = (t & 3) * 160;
        float s1 = 0.f, s2 = 0.f;
        for (int m = m0; m < m0 + 160; ++m) {
            s1 = fmaf(Wq[(size_t)m*CD + o], bk[m], s1);
            s2 = fmaf(bq[m], Wk[(size_t)m*CD + o], s2);
        }
        s1 += __shfl_xor(s1, 1, 64); s1 += __shfl_xor(s1, 2, 64);
        s2 += __shfl_xor(s2, 1, 64); s2 += __shfl_xor(s2, 2, 64);
        if ((t & 3) == 0) { wqtbk[o] = s1; bqwk[o] = s2; }
    } else if (blk < 220) {
        const int o = (blk - 210)*64 + (t >> 2);
        const int m0 = (t & 3) * 160;
        const float* ap = Wq + (size_t)o*CD + m0;
        float a = 0.f;
        for (int m = 0; m < 160; ++m) a = fmaf(ap[m], bc[m0 + m], a);
        a += __shfl_xor(a, 1, 64); a += __shfl_xor(a, 2, 64);
        if ((t & 3) == 0) beff[o] = a + bq[o];
    } else if (blk == 220) {
        __shared__ float red[4];
        float a = 0.f;
        for (int m = t; m < CD; m += 256) a = fmaf(bq[m], bk[m], a);
        for (int off2 = 32; off2; off2 >>= 1) a += __shfl_down(a, off2, 64);
        if ((t & 63) == 0) red[t >> 6] = a;
        __syncthreads();
        if (t == 0) sbb[0] = red[0] + red[1] + red[2] + red[3];
    } else if (blk < 2471) {
        const int idx = blk - 221;
        dev_convert(lf, lfTh, lfTl, idx / 90, idx % 90, smem);
    } else {
        const int i0 = (blk - 2471)*256 + t;
        for (int i = i0; i < 14400; i += 8192) { cor[i] = 0.f; sumsq[i] = 0.f; rvsum[i] = 0.f; }
        for (int i = i0; i < 3200; i += 8192) proto1[i] = 0.f;
        if (i0 < 2) scal[i0] = 0.f;
    }
}

// prep_b: [0,100) M2e=M2*Weff -> MeH/MeL | [100,200) Weff split | [200,210) wbias
__global__ __launch_bounds__(256) void prep_b(
    const float* __restrict__ M2, const float* __restrict__ Weff,
    const float* __restrict__ beff, const float* __restrict__ wqtbk,
    unsigned short* __restrict__ WeH, unsigned short* __restrict__ WeL,
    unsigned short* __restrict__ MeH, unsigned short* __restrict__ MeL,
    float* __restrict__ wbias)
{
    __shared__ __align__(16) char smem[16896];
    const int blk = blockIdx.x;
    const int t = threadIdx.x;
    if (blk < 100) {
        dev_gemm640(M2, Weff, nullptr, nullptr, MeH, MeL, 1, blk % 10, blk / 10, smem);
    } else if (blk < 200) {
        int i = (blk - 100)*256 + t;            // one float4 each, 102400 total
        float4 v = ((const float4*)Weff)[i];
        ushort4 h, l;
        h.x = f2bf(v.x); h.y = f2bf(v.y); h.z = f2bf(v.z); h.w = f2bf(v.w);
        l.x = f2bf(v.x - bf2f(h.x)); l.y = f2bf(v.y - bf2f(h.y));
        l.z = f2bf(v.z - bf2f(h.z)); l.w = f2bf(v.w - bf2f(h.w));
        ((ushort4*)WeH)[i] = h; ((ushort4*)WeL)[i] = l;
    } else {
        const int o = (blk - 200)*64 + (t >> 2);
        const int m0 = (t & 3) * 160;
        const float* ap = M2 + (size_t)o*CD + m0;
        float a = 0.f;
        for (int m = 0; m < 160; ++m) a = fmaf(ap[m], beff[m0 + m], a);
        a += __shfl_xor(a, 1, 64); a += __shfl_xor(a, 2, 64);
        if ((t & 3) == 0) wbias[o] = a + wqtbk[o];
    }
}

// ---------------------------------------------------------------------------
// conv2x: dual-o-tile stacked x5/w GEMM. Each block: one 96-row A-tile staged
// once, TWO 128-col o-tiles (A-frags reused in regs across both).
// acc = 2x3x4 f32x4 = 96 AGPRs (< 128 AGPR half -> no spill; r6 died at 144).
// LDS segs (1KB): Ah 0-5 | Al 6-11 | W0h 12-19 | W0l 20-27 | W1h 28-35 |
// W1l 36-43 = 44KB. grid (5 o-pairs, 150 mtiles), block 256.
// ---------------------------------------------------------------------------
__global__ __launch_bounds__(256) void conv2x(
    const unsigned short* __restrict__ Ah_, const unsigned short* __restrict__ Al_,
    const unsigned short* __restrict__ WeH, const unsigned short* __restrict__ WeL,
    const unsigned short* __restrict__ MeH, const unsigned short* __restrict__ MeL,
    const float* __restrict__ beff, const float* __restrict__ wbias,
    const float* __restrict__ bqwk,
    unsigned short* __restrict__ x5h, unsigned short* __restrict__ x5l,
    unsigned short* __restrict__ wh,  unsigned short* __restrict__ wl,
    float* __restrict__ sumsq, float* __restrict__ rvsum)
{
    __shared__ __align__(16) unsigned short lds[22528];   // 44 KB
    const int row0 = blockIdx.y * 96;
    const int t    = threadIdx.x;
    const int w    = t >> 6, lane = t & 63;
    const int ihalf = (w & 1) * 48;
    const int jhalf = (w >> 1) * 64;

    const int tile0 = blockIdx.x * 2;
    const int tile1 = tile0 + 1;
    const int osel0 = (tile0 < 5), osel1 = (tile1 < 5);
    const int o00 = (tile0 % 5) * 128, o01 = (tile1 % 5) * 128;
    const unsigned short* W0h = osel0 ? WeH : MeH;
    const unsigned short* W0l = osel0 ? WeL : MeL;
    const unsigned short* W1h = osel1 ? WeH : MeH;
    const unsigned short* W1l = osel1 ? WeL : MeL;

    f32x4 acc[2][3][4];
#pragma unroll
    for (int ot = 0; ot < 2; ++ot)
#pragma unroll
        for (int f = 0; f < 3; ++f)
#pragma unroll
            for (int g = 0; g < 4; ++g) acc[ot][f][g] = (f32x4){0.f,0.f,0.f,0.f};

    const int rl = lane >> 2;
    const int cl = (lane & 3) * 8;

    for (int c0 = 0; c0 < CD; c0 += 32) {
#pragma unroll
        for (int e = 0; e < 11; ++e) {
            const int s = w*11 + e;
            const unsigned short* src;
            if (s < 6)        src = Ah_ + (size_t)(row0 + s*16      + rl)*CD + c0 + cl;
            else if (s < 12)  src = Al_ + (size_t)(row0 + (s-6)*16  + rl)*CD + c0 + cl;
            else if (s < 20)  src = W0h + (size_t)(o00  + (s-12)*16 + rl)*CD + c0 + cl;
            else if (s < 28)  src = W0l + (size_t)(o00  + (s-20)*16 + rl)*CD + c0 + cl;
            else if (s < 36)  src = W1h + (size_t)(o01  + (s-28)*16 + rl)*CD + c0 + cl;
            else              src = W1l + (size_t)(o01  + (s-36)*16 + rl)*CD + c0 + cl;
            gload_lds16(src, &lds[s*512]);
        }
        __syncthreads();

        const int chunk = (lane >> 4) * 8;
        short8 afh[3], afl[3];
#pragma unroll
        for (int f = 0; f < 3; ++f) {
            int row = ihalf + f*16 + (lane & 15);
            afh[f] = *(const short8*)&lds[row*32 + chunk];
            afl[f] = *(const short8*)&lds[3072 + row*32 + chunk];
        }
#pragma unroll
        for (int ot = 0; ot < 2; ++ot) {
            const int bh = 6144 + ot*8192;      // W{ot}h base (ushort)
            const int bl = bh + 4096;           // W{ot}l base
#pragma unroll
            for (int g = 0; g < 4; ++g) {
                int row = jhalf + g*16 + (lane & 15);
                short8 bfh = *(const short8*)&lds[bh + row*32 + chunk];
                short8 bfl = *(const short8*)&lds[bl + row*32 + chunk];
#pragma unroll
                for (int f = 0; f < 3; ++f) {
                    acc[ot][f][g] = __builtin_amdgcn_mfma_f32_16x16x32_bf16(afh[f], bfh, acc[ot][f][g], 0, 0, 0);
                    acc[ot][f][g] = __builtin_amdgcn_mfma_f32_16x16x32_bf16(afh[f], bfl, acc[ot][f][g], 0, 0, 0);
                    acc[ot][f][g] = __builtin_amdgcn_mfma_f32_16x16x32_bf16(afl[f], bfh, acc[ot][f][g], 0, 0, 0);
                }
            }
        }
        __syncthreads();
    }

#pragma unroll
    for (int ot = 0; ot < 2; ++ot) {
        const int osel = ot ? osel1 : osel0;
        const int o0   = ot ? o01 : o00;
        const float* bias = osel ? beff : wbias;
        unsigned short* Oh = osel ? x5h : wh;
        unsigned short* Ol = osel ? x5l : wl;
        float bs[4], bw[4];
#pragma unroll
        for (int g = 0; g < 4; ++g) {
            const int o = o0 + jhalf + g*16 + (lane & 15);
            bs[g] = bias[o];
            bw[g] = osel ? bqwk[o] : 0.f;
        }
#pragma unroll
        for (int f = 0; f < 3; ++f) {
            const int rbase = row0 + ihalf + f*16 + (lane >> 4)*4;
#pragma unroll
            for (int r = 0; r < 4; ++r) {
                float sq = 0.f, rv = 0.f;
#pragma unroll
                for (int g = 0; g < 4; ++g) {
                    const int o = o0 + jhalf + g*16 + (lane & 15);
                    const size_t idx = (size_t)(rbase + r)*CD + o;
                    float v = acc[ot][f][g][r] + bs[g];
                    unsigned short hi = f2bf(v);
                    Oh[idx] = hi;
                    Ol[idx] = f2bf(v - bf2f(hi));
                    sq = fmaf(v, v, sq);
                    rv = fmaf(v, bw[g], rv);
                }
                if (osel) {
                    sq += __shfl_xor(sq, 1, 64); rv += __shfl_xor(rv, 1, 64);
                    sq += __shfl_xor(sq, 2, 64); rv += __shfl_xor(rv, 2, 64);
                    sq += __shfl_xor(sq, 4, 64); rv += __shfl_xor(rv, 4, 64);
                    sq += __shfl_xor(sq, 8, 64); rv += __shfl_xor(rv, 8, 64);
                    if ((lane & 15) == 0) {
                        atomicAdd(&sumsq[rbase + r], sq);
                        atomicAdd(&rvsum[rbase + r], rv);
                    }
                }
            }
        }
    }
}

// ---------------------------------------------------------------------------
// qk_mfma: r5-proven 96x192 tiles, rvec = rvsum + sbb, fused shot-max.
// ---------------------------------------------------------------------------
__global__ __launch_bounds__(256) void qk_mfma(
    const unsigned short* __restrict__ Qh, const unsigned short* __restrict__ Ql,
    const unsigned short* __restrict__ Kh, const unsigned short* __restrict__ Kl,
    const float* __restrict__ rvsum, const float* __restrict__ sbb,
    float* __restrict__ xwp)
{
    __shared__ __align__(16) unsigned short lds[18432];     // 36 KB
    const int n    = blockIdx.z;
    const int i0   = blockIdx.x * 96;
    const int shot = blockIdx.y / 3;
    const int jt   = blockIdx.y % 3;
    const int t    = threadIdx.x;
    const int w    = t >> 6, lane = t & 63;
    const int ihalf = (w & 1) * 48;
    const int jhalf = (w >> 1) * 96;

    const size_t qbase = (size_t)(n*NP + i0) * CD;
    const size_t kbase = (size_t)(n*NP + shot*HWD + jt*192) * CD;

    f32x4 acc[3][6];
#pragma unroll
    for (int f = 0; f < 3; ++f)
#pragma unroll
        for (int g = 0; g < 6; ++g) acc[f][g] = (f32x4){0.f,0.f,0.f,0.f};

    const int rl = lane >> 2;
    const int cl = (lane & 3) * 8;

    for (int c0 = 0; c0 < CD; c0 += 32) {
#pragma unroll
        for (int e = 0; e < 9; ++e) {
            const int s = w*9 + e;
            const int r = s*16 + rl;
            const unsigned short* src;
            if (s < 6)        src = Qh + qbase + (size_t)r*CD        + c0 + cl;
            else if (s < 12)  src = Ql + qbase + (size_t)(r-96)*CD   + c0 + cl;
            else if (s < 24)  src = Kh + kbase + (size_t)(r-192)*CD  + c0 + cl;
            else              src = Kl + kbase + (size_t)(r-384)*CD  + c0 + cl;
            gload_lds16(src, &lds[s*512]);
        }
        __syncthreads();

        const int chunk = (lane >> 4) * 8;
        short8 afh[3], afl[3];
#pragma unroll
        for (int f = 0; f < 3; ++f) {
            int row = ihalf + f*16 + (lane & 15);
            afh[f] = *(const short8*)&lds[row*32 + chunk];
            afl[f] = *(const short8*)&lds[3072 + row*32 + chunk];
        }
#pragma unroll
        for (int g = 0; g < 6; ++g) {
            int row = jhalf + g*16 + (lane & 15);
            short8 bfh = *(const short8*)&lds[6144  + row*32 + chunk];
            short8 bfl = *(const short8*)&lds[12288 + row*32 + chunk];
#pragma unroll
            for (int f = 0; f < 3; ++f) {
                acc[f][g] = __builtin_amdgcn_mfma_f32_16x16x32_bf16(afh[f], bfh, acc[f][g], 0, 0, 0);
                acc[f][g] = __builtin_amdgcn_mfma_f32_16x16x32_bf16(afh[f], bfl, acc[f][g], 0, 0, 0);
                acc[f][g] = __builtin_amdgcn_mfma_f32_16x16x32_bf16(afl[f], bfh, acc[f][g], 0, 0, 0);
            }
        }
        __syncthreads();
    }

    const float sv = sbb[0];
    float rv[6];
    {
        int jg0 = n*NP + shot*HWD + jt*192 + jhalf + (lane & 15);
#pragma unroll
        for (int g = 0; g < 6; ++g) rv[g] = rvsum[jg0 + g*16] + sv;
    }
    float* smax = (float*)lds;      // [96][2]
#pragma unroll
    for (int f = 0; f < 3; ++f) {
#pragma unroll
        for (int r = 0; r < 4; ++r) {
            float m = -INFINITY;
#pragma unroll
            for (int g = 0; g < 6; ++g) m = fmaxf(m, acc[f][g][r] + rv[g]);
#pragma unroll
            for (int off = 1; off < 16; off <<= 1) m = fmaxf(m, __shfl_xor(m, off, 64));
            if ((lane & 15) == 0) smax[(ihalf + f*16 + (lane >> 4)*4 + r)*2 + (w >> 1)] = m;
        }
    }
    __syncthreads();
    if (t < 96) {
        float m = fmaxf(smax[t*2], smax[t*2 + 1]);
        xwp[(((size_t)n*5 + shot)*3 + jt)*NP + i0 + t] = m;
    }
}

// ---------------------------------------------------------------------------
// post_a (block 640): [0,90) wide pixel_norms(lf->invnl) | [90,115) argmax+seeds
// ---------------------------------------------------------------------------
__global__ __launch_bounds__(640) void post_a(
    const float* __restrict__ lf, const float* __restrict__ xwp,
    const unsigned short* __restrict__ Xh, const unsigned short* __restrict__ Xl,
    const float* __restrict__ sumsq, float* __restrict__ invnl,
    float* __restrict__ seeds)
{
    const int blk = blockIdx.x;
    const int t = threadIdx.x;
    if (blk < 90) {
        const int pg = blk*160 + (t >> 2);
        const int cb = (t & 3) * 160;
        const int b = pg / HWD, p = pg - (pg / HWD) * HWD;
        const float* sp = lf + (size_t)b*CD*HWD + (size_t)cb*HWD + p;
        float a = 0.f;
        for (int c = 0; c < 160; ++c) { float v = sp[(size_t)c*HWD]; a = fmaf(v, v, a); }
        a += __shfl_xor(a, 1, 64); a += __shfl_xor(a, 2, 64);
        if ((t & 3) == 0) invnl[pg] = 1.f / fmaxf(sqrtf(a), EPSF);
        return;
    }
    const int b = blk - 90;
    const int n = b / NS, sq = b % NS;
    __shared__ float wv[9]; __shared__ int wi[9]; __shared__ int spix;
    if (t < 576) {
        const int i = sq * HWD + t;
        float v = 0.f;
#pragma unroll
        for (int s = 0; s < NS; ++s) {
            float m = -INFINITY;
#pragma unroll
            for (int tt = 0; tt < 3; ++tt)
                m = fmaxf(m, xwp[(((size_t)(n*NS+s))*3 + tt)*NP + i]);
            v += m;
        }
        int lane = t & 63, w = t >> 6;
        float bv = v; int bi = t;
        for (int off = 32; off; off >>= 1) {
            float ov = __shfl_down(bv, off, 64);
            int   oi = __shfl_down(bi, off, 64);
            if (ov > bv || (ov == bv && oi < bi)) { bv = ov; bi = oi; }
        }
        if (lane == 0) { wv[w] = bv; wi[w] = bi; }
    }
    __syncthreads();
    if (t == 0) {
        float best = wv[0]; int bidx = wi[0];
        for (int k = 1; k < 9; ++k)
            if (wv[k] > best || (wv[k] == best && wi[k] < bidx)) { best = wv[k]; bidx = wi[k]; }
        spix = bidx;
    }
    __syncthreads();
    const int row = b*HWD + spix;
    const float in1 = 1.f / fmaxf(sqrtf(sumsq[row]), EPSF);
    float v = bf2f(Xh[(size_t)row*CD + t]) + bf2f(Xl[(size_t)row*CD + t]);
    seeds[b*CD + t] = v * in1;
}

// ---------------------------------------------------------------------------
// post_b (block 256): [0,900) cor_T c-split | [900,4900) masked_sum S_img
// ---------------------------------------------------------------------------
__global__ __launch_bounds__(256) void post_b(
    const unsigned short* __restrict__ Xh, const unsigned short* __restrict__ Xl,
    const float* __restrict__ sumsq, const float* __restrict__ seeds,
    const float* __restrict__ lf, const float* __restrict__ invnl,
    float* __restrict__ cor, float* __restrict__ S_img)
{
    const int blk = blockIdx.x;
    const int t = threadIdx.x;
    if (blk < 900) {
        const int zc = blk / 225, rem = blk % 225;
        const int pb = rem % 9, b = rem / 9;
        const int n = b / NS, k = b % NS;
        const int p = pb*64 + (t >> 2);
        const int row = b*HWD + p;
        const int cb = zc*160 + (t & 3) * 40;
        const unsigned short* ph = Xh + (size_t)row*CD + cb;
        const unsigned short* pl = Xl + (size_t)row*CD + cb;
        float a[5] = {0.f,0.f,0.f,0.f,0.f};
        for (int c = 0; c < 40; c += 8) {
            short8 h8 = *(const short8*)&ph[c];
            short8 l8 = *(const short8*)&pl[c];
#pragma unroll
            for (int j = 0; j < 8; ++j) {
                float v = bf2f((unsigned short)h8[j]) + bf2f((unsigned short)l8[j]);
#pragma unroll
                for (int o = 0; o < 5; ++o)
                    a[o] = fmaf(v, seeds[(o*NS + k)*CD + cb + c + j], a[o]);
            }
        }
        const float in1 = 1.f / fmaxf(sqrtf(sumsq[row]), EPSF);
#pragma unroll
        for (int o = 0; o < 5; ++o) {
            float s = a[o];
            s += __shfl_xor(s, 1, 64); s += __shfl_xor(s, 2, 64);
            if ((t & 3) == 0) atomicAdd(&cor[(n*5 + o)*HWD + p], in1 * s);
        }
        return;
    }
    const int i = blk - 900;                 // masked_sum S_img: 160 ct x 25 b
    const int ct = i % 160, b = i / 160;
    const int pi = t & 63, cj = t >> 6;
    const int c = ct * 4 + cj;
    const float* xp = lf + ((size_t)b * CD + c) * HWD;
    const float* ip = invnl + b * HWD;
    float acc = 0.f;
    for (int p = pi; p < HWD; p += 64) acc = fmaf(xp[p], ip[p], acc);
    for (int off = 32; off; off >>= 1) acc += __shfl_down(acc, off, 64);
    if (pi == 0) S_img[b * CD + c] = acc;
}

// ---------------------------------------------------------------------------
// post_c (block 256): [0,200) proto1 (normalize cor in LDS, row-chunk split,
// atomic accumulate) | [200] sway_stot
// ---------------------------------------------------------------------------
__global__ __launch_bounds__(256) void post_c(
    const unsigned short* __restrict__ Xh, const unsigned short* __restrict__ Xl,
    const float* __restrict__ cor, const float* __restrict__ S_img,
    float* __restrict__ proto1, float* __restrict__ S_way, float* __restrict__ S_tot)
{
    const int blk = blockIdx.x;
    const int t = threadIdx.x;
    if (blk < 200) {
        __shared__ float corb[NP];
        __shared__ float sacc[256];
        __shared__ float mnv[5], mxv[5];
        const int n = blk / 40, rem = blk % 40;
        const int ct = rem % 10, rch = rem / 10;
        for (int j = t; j < NP; j += 256) corb[j] = cor[n*NP + j];
        __syncthreads();
        {
            const int lane = t & 63;
            for (int o = t >> 6; o < 5; o += 4) {
                float mn = INFINITY, mx = -INFINITY;
                for (int j = lane; j < HWD; j += 64) {
                    float v = corb[o*HWD + j];
                    mn = fminf(mn, v); mx = fmaxf(mx, v);
                }
                for (int off = 32; off; off >>= 1) {
                    mn = fminf(mn, __shfl_xor(mn, off, 64));
                    mx = fmaxf(mx, __shfl_xor(mx, off, 64));
                }
                if (lane == 0) { mnv[o] = mn; mxv[o] = mx; }
            }
        }
        __syncthreads();
        for (int j = t; j < NP; j += 256) {
            int o = j / HWD;
            corb[j] = (corb[j] - mnv[o]) / (mxv[o] - mnv[o] + EPSF);
        }
        __syncthreads();
        const int c = ct*64 + (t & 63);
        const int rc = t >> 6;
        const int r0 = rch*720 + rc*180;
        float a = 0.f;
        for (int rr = r0; rr < r0 + 180; ++rr) {
            size_t row = (size_t)(n*NP + rr);
            float v = bf2f(Xh[row*CD + c]) + bf2f(Xl[row*CD + c]);
            a = fmaf(v, corb[rr], a);
        }
        sacc[t] = a;
        __syncthreads();
        if (t < 64) {
            float s = sacc[t] + sacc[t+64] + sacc[t+128] + sacc[t+192];
            atomicAdd(&proto1[n*CD + c], s * (1.f / 2880.f));
        }
        return;
    }
    for (int c = t; c < CD; c += 256) {
        float tot = 0.f;
        for (int nn = 0; nn < NW; ++nn) {
            float w = 0.f;
            for (int s = 0; s < NS; ++s) w += S_img[(nn*NS+s)*CD + c];
            S_way[nn*CD + c] = w; tot += w;
        }
        S_tot[c] = tot;
    }
}

// cds = sigmoid(d_intra/d_inter). grid (9,25), block 256
__global__ __launch_bounds__(256) void cds_v2(const float* __restrict__ lf, const float* __restrict__ invn,
                           const float* __restrict__ S_way, const float* __restrict__ S_img,
                           const float* __restrict__ S_tot, float* __restrict__ cds)
{
    const int b = blockIdx.y, t = threadIdx.x;
    const int p = blockIdx.x*64 + (t >> 2);
    const int cb = (t & 3) * 160;
    const int n = b / NS;
    const float* xp = lf + (size_t)b*CD*HWD + p + (size_t)cb*HWD;
    const float* wv = S_way + n*CD + cb;
    const float* iv = S_img + b*CD + cb;
    const float* tv = S_tot + cb;
    float dw = 0.f, di = 0.f, dt = 0.f, sq = 0.f;
    for (int c = 0; c < 160; ++c) {
        float v = xp[(size_t)c*HWD];
        dw = fmaf(v, wv[c], dw);
        di = fmaf(v, iv[c], di);
        dt = fmaf(v, tv[c], dt);
        sq = fmaf(v, v, sq);
    }
    dw += __shfl_xor(dw,1,64); dw += __shfl_xor(dw,2,64);
    di += __shfl_xor(di,1,64); di += __shfl_xor(di,2,64);
    dt += __shfl_xor(dt,1,64); dt += __shfl_xor(dt,2,64);
    sq += __shfl_xor(sq,1,64); sq += __shfl_xor(sq,2,64);
    if ((t & 3) == 0) {
        float in1 = invn[b*HWD + p];
        float d_intra = (in1 * dw - in1 * in1 * sq) * (1.f / 2880.f);
        float d_inter = (in1 * dt - in1 * di) * (1.f / 14400.f);
        float r = d_intra / d_inter;
        cds[n * NP + (b % NS) * HWD + p] = 1.f / (1.f + expf(-r));
    }
}

// exact top-2304-of-2880 per way: 4-pass byte radix select + jax tie-break. grid 5, block 576
__global__ void topk_kernel(const float* __restrict__ cds, float* __restrict__ sel)
{
    __shared__ unsigned int u[NP];
    __shared__ int hist[256];
    __shared__ int red[16];
    __shared__ int bcast;
    __shared__ unsigned sprefix;
    __shared__ int skk;
    __shared__ int scanbuf[576];
    const int n = blockIdx.x, t = threadIdx.x;
    for (int j = t; j < NP; j += 576) {
        unsigned int x = __float_as_uint(cds[n * NP + j]);
        u[j] = (x & 0x80000000u) ? ~x : (x | 0x80000000u);
    }
    if (t == 0) { skk = KTOP; sprefix = 0u; }
    __syncthreads();
    const int j0 = t * 5;
    for (int byte = 3; byte >= 0; --byte) {
        if (t < 256) hist[t] = 0;
        __syncthreads();
        const int sh = byte * 8;
        const unsigned pmask = (byte == 3) ? 0u : (0xFFFFFFFFu << (sh + 8));
        const unsigned pref = sprefix;
#pragma unroll
        for (int e = 0; e < 5; ++e) {
            unsigned v = u[j0+e];
            if ((v & pmask) == pref) atomicAdd(&hist[(v >> sh) & 255], 1);
        }
        __syncthreads();
        if (t == 0) {
            int kk = skk, acc = 0, b2;
            for (b2 = 255; b2 >= 0; --b2) { acc += hist[b2]; if (acc >= kk) break; }
            skk = kk - (acc - hist[b2]);
            sprefix = pref | ((unsigned)b2 << sh);
        }
        __syncthreads();
    }
    const unsigned int T = sprefix;
    int cg = 0, ce = 0;
#pragma unroll
    for (int e = 0; e < 5; ++e) {
        unsigned v = u[j0+e];
        if (v > T) cg++; else if (v == T) ce++;
    }
    const int lane = t & 63, w = t >> 6;
    int r1 = cg;
    for (int off = 32; off; off >>= 1) r1 += __shfl_down(r1, off, 64);
    if (lane == 0) red[w] = r1;
    __syncthreads();
    if (t == 0) { int s2 = 0; for (int q = 0; q < 9; ++q) s2 += red[q]; bcast = s2; }
    __syncthreads();
    const int need = KTOP - bcast;
    scanbuf[t] = ce;
    __syncthreads();
    for (int off = 1; off < 576; off <<= 1) {
        int v2 = (t >= off) ? scanbuf[t - off] : 0;
        __syncthreads();
        scanbuf[t] += v2;
        __syncthreads();
    }
    int excl = scanbuf[t] - ce;
    int eidx = 0;
#pragma unroll
    for (int e = 0; e < 5; ++e) {
        int j = j0 + e;
        unsigned v = u[j];
        float s = 0.f;
        if (v > T) s = 1.f;
        else if (v == T) { if (excl + eidx < need) s = 1.f; eidx++; }
        int sh2 = j / HWD;
        sel[(n*NS + sh2) * HWD + (j - sh2*HWD)] = s;
    }
}

// post_d (block 256): [0,4000) masked_sum Sm | [4000,4225) ctc | [4225,13225) posindex
__global__ __launch_bounds__(256) void post_d(
    const float* __restrict__ lf, const float* __restrict__ invnl,
    const float* __restrict__ sel, const float* __restrict__ proto1,
    float* __restrict__ Sm, float* __restrict__ scal, float* __restrict__ out)
{
    const int blk = blockIdx.x;
    const int t = threadIdx.x;
    if (blk < 4000) {
        const int ct = blk % 160, b = blk / 160;
        const int pi = t & 63, cj = t >> 6;
        const int c = ct * 4 + cj;
        const float* xp = lf + ((size_t)b * CD + c) * HWD;
        const float* ip = invnl + b * HWD;
        const float* mp = sel + b * HWD;
        float acc = 0.f;
        for (int p = pi; p < HWD; p += 64) acc = fmaf(xp[p], ip[p] * mp[p], acc);
        for (int off = 32; off; off >>= 1) acc += __shfl_down(acc, off, 64);
        if (pi == 0) Sm[b * CD + c] = acc;
        return;
    }
    if (blk < 4225) {
        const int i = blk - 4000;
        const int pb = i % 9, b = i / 9;
        const int p = pb*64 + (t >> 2);
        const int cb = (t & 3) * 160;
        const int n = b / NS;
        const float* xp = lf + (size_t)b*CD*HWD + p + (size_t)cb*HWD;
        const float* pr = proto1 + n*CD + cb;
        float in1 = invnl[b*HWD + p];
        float acc = 0.f;
        for (int c = 0; c < 160; ++c) acc += expf(xp[(size_t)c*HWD] * in1 * pr[c]);
        acc += __shfl_xor(acc, 1, 64); acc += __shfl_xor(acc, 2, 64);
        float pv = 0.f, nv = 0.f;
        if ((t & 3) == 0) {
            float s = sel[b*HWD + p];
            pv = (s > 0.5f) ? acc : 640.f;
            nv = (s > 0.5f) ? 640.f : acc;
        }
        for (int off = 32; off >= 4; off >>= 1) {
            pv += __shfl_down(pv, off, 64);
            nv += __shfl_down(nv, off, 64);
        }
        if ((t & 63) == 0) { atomicAdd(&scal[0], pv); atomicAdd(&scal[1], nv); }
        return;
    }
    // posindex: overlaps the store-bound broadcast with the compute ranges above
    int idx = (blk - 4225) * 256 + t;
    int row = idx / 144;
    int f4  = idx - row * 144;
    int b   = row / CD;
    const float* sp = sel + b * HWD + f4 * 4;
    float* op = out + 2 + (size_t)row * HWD + f4 * 4;
    float2 v0 = make_float2(sp[0], sp[1]);
    float2 v1 = make_float2(sp[2], sp[3]);
    *(float2*)op = v0; *(float2*)(op + 2) = v1;
}

// fin (2 blocks): [0] contrastive loss -> out[0] | [1] ctc loss -> out[1]
__global__ __launch_bounds__(256) void fin_kernel(
    const float* __restrict__ Sm, const float* __restrict__ scal,
    float* __restrict__ out)
{
    const int blk = blockIdx.x;
    const int t = threadIdx.x;
    if (blk == 1) {
        if (t == 0) out[1] = -(logf(scal[0]) - logf(scal[1]));
        return;
    }
    __shared__ double sa[4], sb2[4], sc[4];
    double A = 0.0, Bv = 0.0, Cv = 0.0;
    for (int c = t; c < CD; c += 256) {
        float tot = 0.f;
        for (int nn = 0; nn < NW; ++nn) {
            float ws = 0.f;
            for (int s = 0; s < NS; ++s) {
                float v = Sm[(nn*NS+s)*CD + c];
                ws += v; Cv += (double)v * v;
            }
            tot += ws; A += (double)ws * ws;
        }
        Bv += (double)tot * tot;
    }
    const int lane = t & 63, w = t >> 6;
    for (int off = 32; off; off >>= 1) {
        A  += __shfl_down(A,  off, 64);
        Bv += __shfl_down(Bv, off, 64);
        Cv += __shfl_down(Cv, off, 64);
    }
    if (lane == 0) { sa[w] = A; sb2[w] = Bv; sc[w] = Cv; }
    __syncthreads();
    if (t == 0) {
        double a = 0, b2 = 0, cc = 0;
        for (int q = 0; q < 4; ++q) { a += sa[q]; b2 += sb2[q]; cc += sc[q]; }
        out[0] = (float)exp(5.0 * (a - cc) / (b2 - a));
    }
}

extern "C" void kernel_launch(void* const* d_in, const int* in_sizes, int n_in,
                              void* d_out, int out_size, void* d_ws, size_t ws_size,
                              hipStream_t stream) {
    const float* lf = (const float*)d_in[0];
    const float* Wc = (const float*)d_in[1];
    const float* bc = (const float*)d_in[2];
    const float* Wq = (const float*)d_in[3];
    const float* bq = (const float*)d_in[4];
    const float* Wk = (const float*)d_in[5];
    const float* bk = (const float*)d_in[6];
    float* out = (float*)d_out;
    float* ws = (float*)d_ws;

    const size_t FEAT = 9216000;
    size_t off = 0;
    auto alloc = [&](size_t nf) { float* p = ws + off; off += (nf + 3) & ~(size_t)3; return p; };
    float* s0     = alloc(FEAT);      // x5T h/l
    float* s1     = alloc(FEAT);      // wT h/l (first 819200 f hold fp32 M2/Weff early)
    float* xwp    = alloc(216000);
    float* seeds  = alloc(16000);
    float* invnl  = alloc(14400);
    float* sumsq  = alloc(14400);
    float* rvsum  = alloc(14400);
    float* cor    = alloc(14400);
    float* proto1 = alloc(3200);
    float* S_img  = alloc(16000);
    float* S_way  = alloc(3200);
    float* S_tot  = alloc(640);
    float* cds    = alloc(14400);
    float* sel    = alloc(14400);
    float* Sm     = alloc(16000);
    float* scal   = alloc(8);
    float* wqtbk  = alloc(640);
    float* bqwk   = alloc(640);
    float* sbb    = alloc(4);
    float* beff   = alloc(640);
    float* wbias  = alloc(640);
    float* WeS    = alloc(409600);    // WeffH/L (2x409600 ushort)
    float* MeS    = alloc(409600);    // M2eH/L

    float* M2   = s1;                 // fp32 temporaries, dead before conv2x writes wT
    float* Weff = s1 + 409600;

    unsigned short* WeH = (unsigned short*)WeS; unsigned short* WeL = WeH + 409600;
    unsigned short* MeH = (unsigned short*)MeS; unsigned short* MeL = MeH + 409600;

    // lfT hi/lo in the pos_index output region; overwritten by post_d at the end.
    unsigned short* lfTh = (unsigned short*)(out + 2);
    unsigned short* lfTl = lfTh + FEAT;

    unsigned short* s0h = (unsigned short*)s0; unsigned short* s0l = s0h + FEAT;
    unsigned short* s1h = (unsigned short*)s1; unsigned short* s1l = s1h + FEAT;

    prep_a<<<2503, 256, 0, stream>>>(lf, Wc, bc, Wq, bq, Wk, bk,
                                     M2, Weff, wqtbk, bqwk, beff, sbb,
                                     lfTh, lfTl, cor, sumsq, rvsum, proto1, scal);
    prep_b<<<210, 256, 0, stream>>>(M2, Weff, beff, wqtbk, WeH, WeL, MeH, MeL, wbias);
    conv2x<<<dim3(5,150), 256, 0, stream>>>(lfTh, lfTl, WeH, WeL, MeH, MeL,
                                            beff, wbias, bqwk,
                                            s0h, s0l, s1h, s1l, sumsq, rvsum);
    qk_mfma<<<dim3(30,15,5), 256, 0, stream>>>(s0h, s0l, s1h, s1l, rvsum, sbb, xwp);
    post_a<<<115, 640, 0, stream>>>(lf, xwp, s0h, s0l, sumsq, invnl, seeds);
    post_b<<<4900, 256, 0, stream>>>(s0h, s0l, sumsq, seeds, lf, invnl, cor, S_img);
    post_c<<<201, 256, 0, stream>>>(s0h, s0l, cor, S_img, proto1, S_way, S_tot);
    cds_v2<<<dim3(9,25), 256, 0, stream>>>(lf, invnl, S_way, S_img, S_tot, cds);
    topk_kernel<<<5, 576, 0, stream>>>(cds, sel);
    post_d<<<13225, 256, 0, stream>>>(lf, invnl, sel, proto1, Sm, scal, out);
    fin_kernel<<<2, 256, 0, stream>>>(Sm, scal, out);
}

// Round 11
// 639.529 us; speedup vs baseline: 1.1443x; 1.1443x over previous
//
#include <hip/hip_runtime.h>
#include <math.h>

#define NW 5
#define NS 5
#define BB 25            // NW*NS
#define CD 640
#define HWD 576
#define NP 2880          // NS*HWD
#define KTOP 2304        // int(2880*0.8)
#define EPSF 1e-12f

typedef __attribute__((ext_vector_type(8))) short short8;   // 8 bf16 (4 VGPRs)
typedef __attribute__((ext_vector_type(4))) float f32x4;

__device__ inline unsigned short f2bf(float x) {            // RNE float->bf16
    unsigned u = __float_as_uint(x);
    return (unsigned short)((u + 0x7fffu + ((u >> 16) & 1u)) >> 16);
}
__device__ inline float bf2f(unsigned short h) { return __uint_as_float(((unsigned)h) << 16); }

__device__ inline void gload_lds16(const void* g, void* l) {
    __builtin_amdgcn_global_load_lds(
        (const __attribute__((address_space(1))) unsigned int*)g,
        (__attribute__((address_space(3))) unsigned int*)l, 16, 0, 0);
}

// ---------------------------------------------------------------------------
// device: LDS-tiled fp32 640-GEMM tile. mode0: C=A^T B. mode1: C=A B (+add).
// ---------------------------------------------------------------------------
__device__ void dev_gemm640(const float* __restrict__ A, const float* __restrict__ B,
                            const float* __restrict__ add, float* __restrict__ C,
                            unsigned short* __restrict__ H, unsigned short* __restrict__ L,
                            int mode, int bx, int by, char* smem)
{
    float (*At)[68] = (float(*)[68])smem;            // 32x68
    float (*Bt)[64] = (float(*)[64])(smem + 8704);   // 32x64
    const int o0 = by * 64, j0 = bx * 64;
    const int t  = threadIdx.x;
    const int to = (t >> 4) * 4, tj = (t & 15) * 4;

    float acc[4][4];
#pragma unroll
    for (int r = 0; r < 4; ++r)
#pragma unroll
        for (int s = 0; s < 4; ++s) acc[r][s] = 0.f;

    for (int c0 = 0; c0 < CD; c0 += 32) {
        __syncthreads();
        {
            const int r = t >> 3, c8 = (t & 7) * 8;
            float4 b0 = *(const float4*)&B[(size_t)(c0+r)*CD + j0 + c8];
            float4 b1 = *(const float4*)&B[(size_t)(c0+r)*CD + j0 + c8 + 4];
            *(float4*)&Bt[r][c8]     = b0;
            *(float4*)&Bt[r][c8 + 4] = b1;
            if (mode == 0) {
                float4 a0 = *(const float4*)&A[(size_t)(c0+r)*CD + o0 + c8];
                float4 a1 = *(const float4*)&A[(size_t)(c0+r)*CD + o0 + c8 + 4];
                *(float4*)&At[r][c8]     = a0;
                *(float4*)&At[r][c8 + 4] = a1;
            } else {
                const int r2 = t >> 2, c82 = (t & 3) * 8;
                float4 a0 = *(const float4*)&A[(size_t)(o0+r2)*CD + c0 + c82];
                float4 a1 = *(const float4*)&A[(size_t)(o0+r2)*CD + c0 + c82 + 4];
                At[c82+0][r2] = a0.x; At[c82+1][r2] = a0.y;
                At[c82+2][r2] = a0.z; At[c82+3][r2] = a0.w;
                At[c82+4][r2] = a1.x; At[c82+5][r2] = a1.y;
                At[c82+6][r2] = a1.z; At[c82+7][r2] = a1.w;
            }
        }
        __syncthreads();
#pragma unroll
        for (int kk = 0; kk < 32; ++kk) {
            float4 av = *(const float4*)&At[kk][to];
            float4 bv = *(const float4*)&Bt[kk][tj];
            float aa[4] = {av.x, av.y, av.z, av.w};
            float bb[4] = {bv.x, bv.y, bv.z, bv.w};
#pragma unroll
            for (int r = 0; r < 4; ++r)
#pragma unroll
                for (int s = 0; s < 4; ++s)
                    acc[r][s] = fmaf(aa[r], bb[s], acc[r][s]);
        }
    }

#pragma unroll
    for (int r = 0; r < 4; ++r) {
        float v[4] = {acc[r][0], acc[r][1], acc[r][2], acc[r][3]};
        const size_t base = (size_t)(o0+to+r)*CD + j0 + tj;
        if (add != nullptr) {
            float4 ad = *(const float4*)&add[base];
            v[0] += ad.x; v[1] += ad.y; v[2] += ad.z; v[3] += ad.w;
        }
        if (C != nullptr) {
            float4 o4; o4.x = v[0]; o4.y = v[1]; o4.z = v[2]; o4.w = v[3];
            *(float4*)&C[base] = o4;
        }
        if (H != nullptr) {
            ushort4 h, l;
            h.x = f2bf(v[0]); h.y = f2bf(v[1]); h.z = f2bf(v[2]); h.w = f2bf(v[3]);
            l.x = f2bf(v[0] - bf2f(h.x)); l.y = f2bf(v[1] - bf2f(h.y));
            l.z = f2bf(v[2] - bf2f(h.z)); l.w = f2bf(v[3] - bf2f(h.w));
            *(ushort4*)&H[base] = h; *(ushort4*)&L[base] = l;
        }
    }
}

// device: 64x64 transpose + bf16 hi/lo split of one lf tile
__device__ void dev_convert(const float* __restrict__ in, unsigned short* __restrict__ Oh,
                            unsigned short* __restrict__ Ol, int b, int xidx, char* smem)
{
    float (*tile)[65] = (float(*)[65])smem;
    const int c0 = (xidx / 9) * 64;
    const int p0 = (xidx % 9) * 64;
    const int t  = threadIdx.x;
    const float* src = in + (size_t)b * CD * HWD;
#pragma unroll
    for (int it = 0; it < 4; ++it) {
        int cl = (t >> 4) + 16*it, pl = (t & 15) * 4;
        float4 v = *(const float4*)&src[(size_t)(c0+cl)*HWD + p0 + pl];
        tile[cl][pl] = v.x; tile[cl][pl+1] = v.y; tile[cl][pl+2] = v.z; tile[cl][pl+3] = v.w;
    }
    __syncthreads();
#pragma unroll
    for (int it = 0; it < 4; ++it) {
        int pl = (t >> 4) + 16*it, clb = (t & 15) * 4;
        ushort4 hv, lv;
        float x0 = tile[clb+0][pl], x1 = tile[clb+1][pl], x2 = tile[clb+2][pl], x3 = tile[clb+3][pl];
        hv.x = f2bf(x0); hv.y = f2bf(x1); hv.z = f2bf(x2); hv.w = f2bf(x3);
        lv.x = f2bf(x0 - bf2f(hv.x)); lv.y = f2bf(x1 - bf2f(hv.y));
        lv.z = f2bf(x2 - bf2f(hv.z)); lv.w = f2bf(x3 - bf2f(hv.w));
        size_t o = (size_t)(b*HWD + p0 + pl) * CD + c0 + clb;
        *(ushort4*)&Oh[o] = hv;
        *(ushort4*)&Ol[o] = lv;
    }
}

// ---------------------------------------------------------------------------
// prep_a: [0,100) M2=Wq^T Wk | [100,200) Weff=Wq*Wc+Wq | [200,210) wqtbk/bqwk
// [210,220) beff | [220] sbb | [221,2471) convert_t(lf) | [2471,2503) zeros
// [2503,2728) invnl (lf pixel norms — independent, feeds cdsnet path)
// ---------------------------------------------------------------------------
__global__ __launch_bounds__(256) void prep_a(
    const float* __restrict__ lf, const float* __restrict__ Wc,
    const float* __restrict__ bc, const float* __restrict__ Wq,
    const float* __restrict__ bq, const float* __restrict__ Wk,
    const float* __restrict__ bk,
    float* __restrict__ M2, float* __restrict__ Weff,
    float* __restrict__ wqtbk, float* __restrict__ bqwk, float* __restrict__ beff,
    float* __restrict__ sbb,
    unsigned short* __restrict__ lfTh, unsigned short* __restrict__ lfTl,
    float* __restrict__ cor, float* __restrict__ sumsq, float* __restrict__ rvsum,
    float* __restrict__ proto1, float* __restrict__ scal, float* __restrict__ invnl)
{
    __shared__ __align__(16) char smem[16896];
    const int blk = blockIdx.x;
    const int t = threadIdx.x;
    if (blk < 100) {
        dev_gemm640(Wq, Wk, nullptr, M2, nullptr, nullptr, 0, blk % 10, blk / 10, smem);
    } else if (blk < 200) {
        int b2 = blk - 100;
        dev_gemm640(Wq, Wc, Wq, Weff, nullptr, nullptr, 1, b2 % 10, b2 / 10, smem);
    } else if (blk < 210) {
        const int o = (blk - 200)*64 + (t >> 2);
        const int m0 = (t & 3) * 160;
        float s1 = 0.f, s2 = 0.f;
        for (int m = m0; m < m0 + 160; ++m) {
            s1 = fmaf(Wq[(size_t)m*CD + o], bk[m], s1);
            s2 = fmaf(bq[m], Wk[(size_t)m*CD + o], s2);
        }
        s1 += __shfl_xor(s1, 1, 64); s1 += __shfl_xor(s1, 2, 64);
        s2 += __shfl_xor(s2, 1, 64); s2 += __shfl_xor(s2, 2, 64);
        if ((t & 3) == 0) { wqtbk[o] = s1; bqwk[o] = s2; }
    } else if (blk < 220) {
        const int o = (blk - 210)*64 + (t >> 2);
        const int m0 = (t & 3) * 160;
        const float* ap = Wq + (size_t)o*CD + m0;
        float a = 0.f;
        for (int m = 0; m < 160; ++m) a = fmaf(ap[m], bc[m0 + m], a);
        a += __shfl_xor(a, 1, 64); a += __shfl_xor(a, 2, 64);
        if ((t & 3) == 0) beff[o] = a + bq[o];
    } else if (blk == 220) {
        __shared__ float red[4];
        float a = 0.f;
        for (int m = t; m < CD; m += 256) a = fmaf(bq[m], bk[m], a);
        for (int off2 = 32; off2; off2 >>= 1) a += __shfl_down(a, off2, 64);
        if ((t & 63) == 0) red[t >> 6] = a;
        __syncthreads();
        if (t == 0) sbb[0] = red[0] + red[1] + red[2] + red[3];
    } else if (blk < 2471) {
        const int idx = blk - 221;
        dev_convert(lf, lfTh, lfTl, idx / 90, idx % 90, smem);
    } else if (blk < 2503) {
        const int i0 = (blk - 2471)*256 + t;
        for (int i = i0; i < 14400; i += 8192) { cor[i] = 0.f; sumsq[i] = 0.f; rvsum[i] = 0.f; }
        for (int i = i0; i < 3200; i += 8192) proto1[i] = 0.f;
        if (i0 < 2) scal[i0] = 0.f;
    } else {
        const int idx = blk - 2503;              // pixel norms on lf: 225 blocks
        const int pb = idx % 9, b = idx / 9;
        const int p = pb*64 + (t >> 2);
        const int cb = (t & 3) * 160;
        const float* sp = lf + (size_t)b*CD*HWD + p + (size_t)cb*HWD;
        float a = 0.f;
        for (int c = 0; c < 160; ++c) { float v = sp[(size_t)c*HWD]; a = fmaf(v, v, a); }
        a += __shfl_xor(a, 1, 64); a += __shfl_xor(a, 2, 64);
        if ((t & 3) == 0) invnl[b*HWD + p] = 1.f / fmaxf(sqrtf(a), EPSF);
    }
}

// prep_b: [0,100) M2e=M2*Weff -> MeH/MeL | [100,200) Weff split | [200,210) wbias
__global__ __launch_bounds__(256) void prep_b(
    const float* __restrict__ M2, const float* __restrict__ Weff,
    const float* __restrict__ beff, const float* __restrict__ wqtbk,
    unsigned short* __restrict__ WeH, unsigned short* __restrict__ WeL,
    unsigned short* __restrict__ MeH, unsigned short* __restrict__ MeL,
    float* __restrict__ wbias)
{
    __shared__ __align__(16) char smem[16896];
    const int blk = blockIdx.x;
    const int t = threadIdx.x;
    if (blk < 100) {
        dev_gemm640(M2, Weff, nullptr, nullptr, MeH, MeL, 1, blk % 10, blk / 10, smem);
    } else if (blk < 200) {
        int i = (blk - 100)*256 + t;
        float4 v = ((const float4*)Weff)[i];
        ushort4 h, l;
        h.x = f2bf(v.x); h.y = f2bf(v.y); h.z = f2bf(v.z); h.w = f2bf(v.w);
        l.x = f2bf(v.x - bf2f(h.x)); l.y = f2bf(v.y - bf2f(h.y));
        l.z = f2bf(v.z - bf2f(h.z)); l.w = f2bf(v.w - bf2f(h.w));
        ((ushort4*)WeH)[i] = h; ((ushort4*)WeL)[i] = l;
    } else {
        const int o = (blk - 200)*64 + (t >> 2);
        const int m0 = (t & 3) * 160;
        const float* ap = M2 + (size_t)o*CD + m0;
        float a = 0.f;
        for (int m = 0; m < 160; ++m) a = fmaf(ap[m], beff[m0 + m], a);
        a += __shfl_xor(a, 1, 64); a += __shfl_xor(a, 2, 64);
        if ((t & 3) == 0) wbias[o] = a + wqtbk[o];
    }
}

// ---------------------------------------------------------------------------
// conv2x: r9-proven single-o-tile stacked x5/w GEMM (96x128, LDS 28KB) + fused
// per-row sumsq/rvec partials. grid (10 otiles, 150 mtiles), block 256.
// ---------------------------------------------------------------------------
__global__ __launch_bounds__(256) void conv2x(
    const unsigned short* __restrict__ Ah_, const unsigned short* __restrict__ Al_,
    const unsigned short* __restrict__ WeH, const unsigned short* __restrict__ WeL,
    const unsigned short* __restrict__ MeH, const unsigned short* __restrict__ MeL,
    const float* __restrict__ beff, const float* __restrict__ wbias,
    const float* __restrict__ bqwk,
    unsigned short* __restrict__ x5h, unsigned short* __restrict__ x5l,
    unsigned short* __restrict__ wh,  unsigned short* __restrict__ wl,
    float* __restrict__ sumsq, float* __restrict__ rvsum)
{
    __shared__ __align__(16) unsigned short lds[14336];
    const int obx  = blockIdx.x;
    const int osel = (obx < 5);
    const int o0   = (osel ? obx : obx - 5) * 128;
    const unsigned short* Wh = osel ? WeH : MeH;
    const unsigned short* Wl = osel ? WeL : MeL;
    const float* bias = osel ? beff : wbias;
    unsigned short* Oh = osel ? x5h : wh;
    unsigned short* Ol = osel ? x5l : wl;
    const int row0 = blockIdx.y * 96;
    const int t    = threadIdx.x;
    const int w    = t >> 6, lane = t & 63;
    const int ihalf = (w & 1) * 48;
    const int jhalf = (w >> 1) * 64;

    f32x4 acc[3][4];
#pragma unroll
    for (int f = 0; f < 3; ++f)
#pragma unroll
        for (int g = 0; g < 4; ++g) acc[f][g] = (f32x4){0.f,0.f,0.f,0.f};

    const int rl = lane >> 2;
    const int cl = (lane & 3) * 8;

    for (int c0 = 0; c0 < CD; c0 += 32) {
#pragma unroll
        for (int e = 0; e < 7; ++e) {
            const int s = w*7 + e;
            const unsigned short* src;
            if (s < 6)        src = Ah_ + (size_t)(row0 + s*16      + rl)*CD + c0 + cl;
            else if (s < 12)  src = Al_ + (size_t)(row0 + (s-6)*16  + rl)*CD + c0 + cl;
            else if (s < 20)  src = Wh  + (size_t)(o0   + (s-12)*16 + rl)*CD + c0 + cl;
            else              src = Wl  + (size_t)(o0   + (s-20)*16 + rl)*CD + c0 + cl;
            gload_lds16(src, &lds[s*512]);
        }
        __syncthreads();

        const int chunk = (lane >> 4) * 8;
        short8 afh[3], afl[3];
#pragma unroll
        for (int f = 0; f < 3; ++f) {
            int row = ihalf + f*16 + (lane & 15);
            afh[f] = *(const short8*)&lds[row*32 + chunk];
            afl[f] = *(const short8*)&lds[3072 + row*32 + chunk];
        }
#pragma unroll
        for (int g = 0; g < 4; ++g) {
            int row = jhalf + g*16 + (lane & 15);
            short8 bfh = *(const short8*)&lds[6144  + row*32 + chunk];
            short8 bfl = *(const short8*)&lds[10240 + row*32 + chunk];
#pragma unroll
            for (int f = 0; f < 3; ++f) {
                acc[f][g] = __builtin_amdgcn_mfma_f32_16x16x32_bf16(afh[f], bfh, acc[f][g], 0, 0, 0);
                acc[f][g] = __builtin_amdgcn_mfma_f32_16x16x32_bf16(afh[f], bfl, acc[f][g], 0, 0, 0);
                acc[f][g] = __builtin_amdgcn_mfma_f32_16x16x32_bf16(afl[f], bfh, acc[f][g], 0, 0, 0);
            }
        }
        __syncthreads();
    }

    float bs[4], bw[4];
#pragma unroll
    for (int g = 0; g < 4; ++g) {
        const int o = o0 + jhalf + g*16 + (lane & 15);
        bs[g] = bias[o];
        bw[g] = osel ? bqwk[o] : 0.f;
    }
#pragma unroll
    for (int f = 0; f < 3; ++f) {
        const int rbase = row0 + ihalf + f*16 + (lane >> 4)*4;
#pragma unroll
        for (int r = 0; r < 4; ++r) {
            float sq = 0.f, rv = 0.f;
#pragma unroll
            for (int g = 0; g < 4; ++g) {
                const int o = o0 + jhalf + g*16 + (lane & 15);
                const size_t idx = (size_t)(rbase + r)*CD + o;
                float v = acc[f][g][r] + bs[g];
                unsigned short hi = f2bf(v);
                Oh[idx] = hi;
                Ol[idx] = f2bf(v - bf2f(hi));
                sq = fmaf(v, v, sq);
                rv = fmaf(v, bw[g], rv);
            }
            if (osel) {
                sq += __shfl_xor(sq, 1, 64); rv += __shfl_xor(rv, 1, 64);
                sq += __shfl_xor(sq, 2, 64); rv += __shfl_xor(rv, 2, 64);
                sq += __shfl_xor(sq, 4, 64); rv += __shfl_xor(rv, 4, 64);
                sq += __shfl_xor(sq, 8, 64); rv += __shfl_xor(rv, 8, 64);
                if ((lane & 15) == 0) {
                    atomicAdd(&sumsq[rbase + r], sq);
                    atomicAdd(&rvsum[rbase + r], rv);
                }
            }
        }
    }
}

// ---------------------------------------------------------------------------
// qk_mega: [0,2250) QK^T (r5-proven 96x192, fused shot-max) | [2250,6250)
// S_img masked_sum over lf (independent cdsnet work, overlaps qk's compute).
// ---------------------------------------------------------------------------
__global__ __launch_bounds__(256) void qk_mega(
    const unsigned short* __restrict__ Qh, const unsigned short* __restrict__ Ql,
    const unsigned short* __restrict__ Kh, const unsigned short* __restrict__ Kl,
    const float* __restrict__ rvsum, const float* __restrict__ sbb,
    const float* __restrict__ lf, const float* __restrict__ invnl,
    float* __restrict__ xwp, float* __restrict__ S_img)
{
    __shared__ __align__(16) unsigned short lds[18432];     // 36 KB (qk range)
    const int blk = blockIdx.x;
    const int t   = threadIdx.x;
    if (blk >= 2250) {
        const int i = blk - 2250;            // S_img: 160 ct x 25 b
        const int ct = i % 160, b = i / 160;
        const int pi = t & 63, cj = t >> 6;
        const int c = ct * 4 + cj;
        const float* xp = lf + ((size_t)b * CD + c) * HWD;
        const float* ip = invnl + b * HWD;
        float acc = 0.f;
        for (int p = pi; p < HWD; p += 64) acc = fmaf(xp[p], ip[p], acc);
        for (int off = 32; off; off >>= 1) acc += __shfl_down(acc, off, 64);
        if (pi == 0) S_img[b * CD + c] = acc;
        return;
    }
    const int n    = blk / 450;
    const int yy   = (blk / 30) % 15;
    const int i0   = (blk % 30) * 96;
    const int shot = yy / 3;
    const int jt   = yy % 3;
    const int w    = t >> 6, lane = t & 63;
    const int ihalf = (w & 1) * 48;
    const int jhalf = (w >> 1) * 96;

    const size_t qbase = (size_t)(n*NP + i0) * CD;
    const size_t kbase = (size_t)(n*NP + shot*HWD + jt*192) * CD;

    f32x4 acc[3][6];
#pragma unroll
    for (int f = 0; f < 3; ++f)
#pragma unroll
        for (int g = 0; g < 6; ++g) acc[f][g] = (f32x4){0.f,0.f,0.f,0.f};

    const int rl = lane >> 2;
    const int cl = (lane & 3) * 8;

    for (int c0 = 0; c0 < CD; c0 += 32) {
#pragma unroll
        for (int e = 0; e < 9; ++e) {
            const int s = w*9 + e;
            const int r = s*16 + rl;
            const unsigned short* src;
            if (s < 6)        src = Qh + qbase + (size_t)r*CD        + c0 + cl;
            else if (s < 12)  src = Ql + qbase + (size_t)(r-96)*CD   + c0 + cl;
            else if (s < 24)  src = Kh + kbase + (size_t)(r-192)*CD  + c0 + cl;
            else              src = Kl + kbase + (size_t)(r-384)*CD  + c0 + cl;
            gload_lds16(src, &lds[s*512]);
        }
        __syncthreads();

        const int chunk = (lane >> 4) * 8;
        short8 afh[3], afl[3];
#pragma unroll
        for (int f = 0; f < 3; ++f) {
            int row = ihalf + f*16 + (lane & 15);
            afh[f] = *(const short8*)&lds[row*32 + chunk];
            afl[f] = *(const short8*)&lds[3072 + row*32 + chunk];
        }
#pragma unroll
        for (int g = 0; g < 6; ++g) {
            int row = jhalf + g*16 + (lane & 15);
            short8 bfh = *(const short8*)&lds[6144  + row*32 + chunk];
            short8 bfl = *(const short8*)&lds[12288 + row*32 + chunk];
#pragma unroll
            for (int f = 0; f < 3; ++f) {
                acc[f][g] = __builtin_amdgcn_mfma_f32_16x16x32_bf16(afh[f], bfh, acc[f][g], 0, 0, 0);
                acc[f][g] = __builtin_amdgcn_mfma_f32_16x16x32_bf16(afh[f], bfl, acc[f][g], 0, 0, 0);
                acc[f][g] = __builtin_amdgcn_mfma_f32_16x16x32_bf16(afl[f], bfh, acc[f][g], 0, 0, 0);
            }
        }
        __syncthreads();
    }

    const float sv = sbb[0];
    float rv[6];
    {
        int jg0 = n*NP + shot*HWD + jt*192 + jhalf + (lane & 15);
#pragma unroll
        for (int g = 0; g < 6; ++g) rv[g] = rvsum[jg0 + g*16] + sv;
    }
    float* smax = (float*)lds;      // [96][2]
#pragma unroll
    for (int f = 0; f < 3; ++f) {
#pragma unroll
        for (int r = 0; r < 4; ++r) {
            float m = -INFINITY;
#pragma unroll
            for (int g = 0; g < 6; ++g) m = fmaxf(m, acc[f][g][r] + rv[g]);
#pragma unroll
            for (int off = 1; off < 16; off <<= 1) m = fmaxf(m, __shfl_xor(m, off, 64));
            if ((lane & 15) == 0) smax[(ihalf + f*16 + (lane >> 4)*4 + r)*2 + (w >> 1)] = m;
        }
    }
    __syncthreads();
    if (t < 96) {
        float m = fmaxf(smax[t*2], smax[t*2 + 1]);
        xwp[(((size_t)n*5 + shot)*3 + jt)*NP + i0 + t] = m;
    }
}

// ---------------------------------------------------------------------------
// post_1 (block 256): [0,25) argmax + seeds gather | [25] sway_stot
// ---------------------------------------------------------------------------
__global__ __launch_bounds__(256) void post_1(
    const float* __restrict__ xwp,
    const unsigned short* __restrict__ Xh, const unsigned short* __restrict__ Xl,
    const float* __restrict__ sumsq, const float* __restrict__ S_img,
    float* __restrict__ seeds, float* __restrict__ S_way, float* __restrict__ S_tot)
{
    const int blk = blockIdx.x;
    const int t = threadIdx.x;
    if (blk < 25) {
        const int b = blk;
        const int n = b / NS, sq = b % NS;
        __shared__ float wv[4]; __shared__ int wi[4]; __shared__ int spix;
        float bv = -INFINITY; int bi = 0x7fffffff;
        for (int p = t; p < HWD; p += 256) {
            const int i = sq * HWD + p;
            float v = 0.f;
#pragma unroll
            for (int s = 0; s < NS; ++s) {
                float m = -INFINITY;
#pragma unroll
                for (int tt = 0; tt < 3; ++tt)
                    m = fmaxf(m, xwp[(((size_t)(n*NS+s))*3 + tt)*NP + i]);
                v += m;
            }
            if (v > bv) { bv = v; bi = p; }     // increasing p => lowest-index tie-break
        }
        const int lane = t & 63, w = t >> 6;
        for (int off = 32; off; off >>= 1) {
            float ov = __shfl_down(bv, off, 64);
            int   oi = __shfl_down(bi, off, 64);
            if (ov > bv || (ov == bv && oi < bi)) { bv = ov; bi = oi; }
        }
        if (lane == 0) { wv[w] = bv; wi[w] = bi; }
        __syncthreads();
        if (t == 0) {
            float best = wv[0]; int bidx = wi[0];
            for (int k = 1; k < 4; ++k)
                if (wv[k] > best || (wv[k] == best && wi[k] < bidx)) { best = wv[k]; bidx = wi[k]; }
            spix = bidx;
        }
        __syncthreads();
        const int row = b*HWD + spix;
        const float in1 = 1.f / fmaxf(sqrtf(sumsq[row]), EPSF);
        for (int c = t; c < CD; c += 256) {
            float v = bf2f(Xh[(size_t)row*CD + c]) + bf2f(Xl[(size_t)row*CD + c]);
            seeds[b*CD + c] = v * in1;
        }
        return;
    }
    for (int c = t; c < CD; c += 256) {
        float tot = 0.f;
        for (int nn = 0; nn < NW; ++nn) {
            float w2 = 0.f;
            for (int s = 0; s < NS; ++s) w2 += S_img[(nn*NS+s)*CD + c];
            S_way[nn*CD + c] = w2; tot += w2;
        }
        S_tot[c] = tot;
    }
}

// ---------------------------------------------------------------------------
// post_2 (block 256): [0,900) cor_T c-split | [900,1125) cds
// ---------------------------------------------------------------------------
__global__ __launch_bounds__(256) void post_2(
    const unsigned short* __restrict__ Xh, const unsigned short* __restrict__ Xl,
    const float* __restrict__ sumsq, const float* __restrict__ seeds,
    const float* __restrict__ lf, const float* __restrict__ invnl,
    const float* __restrict__ S_way, const float* __restrict__ S_img,
    const float* __restrict__ S_tot,
    float* __restrict__ cor, float* __restrict__ cds)
{
    const int blk = blockIdx.x;
    const int t = threadIdx.x;
    if (blk < 900) {
        const int zc = blk / 225, rem = blk % 225;
        const int pb = rem % 9, b = rem / 9;
        const int n = b / NS, k = b % NS;
        const int p = pb*64 + (t >> 2);
        const int row = b*HWD + p;
        const int cb = zc*160 + (t & 3) * 40;
        const unsigned short* ph = Xh + (size_t)row*CD + cb;
        const unsigned short* pl = Xl + (size_t)row*CD + cb;
        float a[5] = {0.f,0.f,0.f,0.f,0.f};
        for (int c = 0; c < 40; c += 8) {
            short8 h8 = *(const short8*)&ph[c];
            short8 l8 = *(const short8*)&pl[c];
#pragma unroll
            for (int j = 0; j < 8; ++j) {
                float v = bf2f((unsigned short)h8[j]) + bf2f((unsigned short)l8[j]);
#pragma unroll
                for (int o = 0; o < 5; ++o)
                    a[o] = fmaf(v, seeds[(o*NS + k)*CD + cb + c + j], a[o]);
            }
        }
        const float in1 = 1.f / fmaxf(sqrtf(sumsq[row]), EPSF);
#pragma unroll
        for (int o = 0; o < 5; ++o) {
            float s = a[o];
            s += __shfl_xor(s, 1, 64); s += __shfl_xor(s, 2, 64);
            if ((t & 3) == 0) atomicAdd(&cor[(n*5 + o)*HWD + p], in1 * s);
        }
        return;
    }
    const int idx = blk - 900;
    const int pb = idx % 9, b = idx / 9;
    const int p = pb*64 + (t >> 2);
    const int cb = (t & 3) * 160;
    const int n = b / NS;
    const float* xp = lf + (size_t)b*CD*HWD + p + (size_t)cb*HWD;
    const float* wv = S_way + n*CD + cb;
    const float* iv = S_img + b*CD + cb;
    const float* tv = S_tot + cb;
    float dw = 0.f, di = 0.f, dt = 0.f, sq = 0.f;
    for (int c = 0; c < 160; ++c) {
        float v = xp[(size_t)c*HWD];
        dw = fmaf(v, wv[c], dw);
        di = fmaf(v, iv[c], di);
        dt = fmaf(v, tv[c], dt);
        sq = fmaf(v, v, sq);
    }
    dw += __shfl_xor(dw,1,64); dw += __shfl_xor(dw,2,64);
    di += __shfl_xor(di,1,64); di += __shfl_xor(di,2,64);
    dt += __shfl_xor(dt,1,64); dt += __shfl_xor(dt,2,64);
    sq += __shfl_xor(sq,1,64); sq += __shfl_xor(sq,2,64);
    if ((t & 3) == 0) {
        float in1 = invnl[b*HWD + p];
        float d_intra = (in1 * dw - in1 * in1 * sq) * (1.f / 2880.f);
        float d_inter = (in1 * dt - in1 * di) * (1.f / 14400.f);
        float r = d_intra / d_inter;
        cds[n * NP + (b % NS) * HWD + p] = 1.f / (1.f + expf(-r));
    }
}

// ---------------------------------------------------------------------------
// post_3 (block 576): [0,5) topk | [5,55) proto1 (minmax-normalize cor in LDS,
// direct store). Independent ranges (topk<-cds, proto1<-cor).
// ---------------------------------------------------------------------------
__global__ __launch_bounds__(576) void post_3(
    const float* __restrict__ cds,
    const unsigned short* __restrict__ Xh, const unsigned short* __restrict__ Xl,
    const float* __restrict__ cor,
    float* __restrict__ sel, float* __restrict__ proto1)
{
    __shared__ unsigned int u[NP];
    __shared__ int hist[256];
    __shared__ int red[16];
    __shared__ int bcast;
    __shared__ unsigned sprefix;
    __shared__ int skk;
    __shared__ int scanbuf[576];
    __shared__ float corb[NP];
    __shared__ float sacc[576];
    __shared__ float mnv[5], mxv[5];
    const int blk = blockIdx.x;
    const int t = threadIdx.x;
    if (blk >= 5) {
        const int idx = blk - 5;
        const int n = idx / 10, ct = idx % 10;
        for (int j = t; j < NP; j += 576) corb[j] = cor[n*NP + j];
        __syncthreads();
        if (t < 320) {
            const int o = t >> 6, lane = t & 63;
            float mn = INFINITY, mx = -INFINITY;
            for (int j = lane; j < HWD; j += 64) {
                float v = corb[o*HWD + j];
                mn = fminf(mn, v); mx = fmaxf(mx, v);
            }
            for (int off = 32; off; off >>= 1) {
                mn = fminf(mn, __shfl_xor(mn, off, 64));
                mx = fmaxf(mx, __shfl_xor(mx, off, 64));
            }
            if (lane == 0) { mnv[o] = mn; mxv[o] = mx; }
        }
        __syncthreads();
        for (int j = t; j < NP; j += 576) {
            int o = j / HWD;
            corb[j] = (corb[j] - mnv[o]) / (mxv[o] - mnv[o] + EPSF);
        }
        __syncthreads();
        const int c = ct*64 + (t & 63);
        const int rc = t >> 6;                  // 0..8, 9 chunks of 320 rows
        float a = 0.f;
        for (int rr = rc*320; rr < rc*320 + 320; ++rr) {
            size_t row = (size_t)(n*NP + rr);
            float v = bf2f(Xh[row*CD + c]) + bf2f(Xl[row*CD + c]);
            a = fmaf(v, corb[rr], a);
        }
        sacc[t] = a;
        __syncthreads();
        if (t < 64) {
            float s = 0.f;
            for (int q = 0; q < 9; ++q) s += sacc[t + 64*q];
            proto1[n*CD + ct*64 + t] = s * (1.f / 2880.f);
        }
        return;
    }
    const int n = blk;
    for (int j = t; j < NP; j += 576) {
        unsigned int x = __float_as_uint(cds[n * NP + j]);
        u[j] = (x & 0x80000000u) ? ~x : (x | 0x80000000u);
    }
    if (t == 0) { skk = KTOP; sprefix = 0u; }
    __syncthreads();
    const int j0 = t * 5;
    for (int byte = 3; byte >= 0; --byte) {
        if (t < 256) hist[t] = 0;
        __syncthreads();
        const int sh = byte * 8;
        const unsigned pmask = (byte == 3) ? 0u : (0xFFFFFFFFu << (sh + 8));
        const unsigned pref = sprefix;
#pragma unroll
        for (int e = 0; e < 5; ++e) {
            unsigned v = u[j0+e];
            if ((v & pmask) == pref) atomicAdd(&hist[(v >> sh) & 255], 1);
        }
        __syncthreads();
        if (t == 0) {
            int kk = skk, acc = 0, b2;
            for (b2 = 255; b2 >= 0; --b2) { acc += hist[b2]; if (acc >= kk) break; }
            skk = kk - (acc - hist[b2]);
            sprefix = pref | ((unsigned)b2 << sh);
        }
        __syncthreads();
    }
    const unsigned int T = sprefix;
    int cg = 0, ce = 0;
#pragma unroll
    for (int e = 0; e < 5; ++e) {
        unsigned v = u[j0+e];
        if (v > T) cg++; else if (v == T) ce++;
    }
    const int lane = t & 63, w = t >> 6;
    int r1 = cg;
    for (int off = 32; off; off >>= 1) r1 += __shfl_down(r1, off, 64);
    if (lane == 0) red[w] = r1;
    __syncthreads();
    if (t == 0) { int s2 = 0; for (int q = 0; q < 9; ++q) s2 += red[q]; bcast = s2; }
    __syncthreads();
    const int need = KTOP - bcast;
    scanbuf[t] = ce;
    __syncthreads();
    for (int off = 1; off < 576; off <<= 1) {
        int v2 = (t >= off) ? scanbuf[t - off] : 0;
        __syncthreads();
        scanbuf[t] += v2;
        __syncthreads();
    }
    int excl = scanbuf[t] - ce;
    int eidx = 0;
#pragma unroll
    for (int e = 0; e < 5; ++e) {
        int j = j0 + e;
        unsigned v = u[j];
        float s = 0.f;
        if (v > T) s = 1.f;
        else if (v == T) { if (excl + eidx < need) s = 1.f; eidx++; }
        int sh2 = j / HWD;
        sel[(n*NS + sh2) * HWD + (j - sh2*HWD)] = s;
    }
}

// post_4 (block 256): [0,4000) masked_sum Sm | [4000,4225) ctc | [4225,13225) posindex
__global__ __launch_bounds__(256) void post_4(
    const float* __restrict__ lf, const float* __restrict__ invnl,
    const float* __restrict__ sel, const float* __restrict__ proto1,
    float* __restrict__ Sm, float* __restrict__ scal, float* __restrict__ out)
{
    const int blk = blockIdx.x;
    const int t = threadIdx.x;
    if (blk < 4000) {
        const int ct = blk % 160, b = blk / 160;
        const int pi = t & 63, cj = t >> 6;
        const int c = ct * 4 + cj;
        const float* xp = lf + ((size_t)b * CD + c) * HWD;
        const float* ip = invnl + b * HWD;
        const float* mp = sel + b * HWD;
        float acc = 0.f;
        for (int p = pi; p < HWD; p += 64) acc = fmaf(xp[p], ip[p] * mp[p], acc);
        for (int off = 32; off; off >>= 1) acc += __shfl_down(acc, off, 64);
        if (pi == 0) Sm[b * CD + c] = acc;
        return;
    }
    if (blk < 4225) {
        const int i = blk - 4000;
        const int pb = i % 9, b = i / 9;
        const int p = pb*64 + (t >> 2);
        const int cb = (t & 3) * 160;
        const int n = b / NS;
        const float* xp = lf + (size_t)b*CD*HWD + p + (size_t)cb*HWD;
        const float* pr = proto1 + n*CD + cb;
        float in1 = invnl[b*HWD + p];
        float acc = 0.f;
        for (int c = 0; c < 160; ++c) acc += expf(xp[(size_t)c*HWD] * in1 * pr[c]);
        acc += __shfl_xor(acc, 1, 64); acc += __shfl_xor(acc, 2, 64);
        float pv = 0.f, nv = 0.f;
        if ((t & 3) == 0) {
            float s = sel[b*HWD + p];
            pv = (s > 0.5f) ? acc : 640.f;
            nv = (s > 0.5f) ? 640.f : acc;
        }
        for (int off = 32; off >= 4; off >>= 1) {
            pv += __shfl_down(pv, off, 64);
            nv += __shfl_down(nv, off, 64);
        }
        if ((t & 63) == 0) { atomicAdd(&scal[0], pv); atomicAdd(&scal[1], nv); }
        return;
    }
    int idx = (blk - 4225) * 256 + t;
    int row = idx / 144;
    int f4  = idx - row * 144;
    int b   = row / CD;
    const float* sp = sel + b * HWD + f4 * 4;
    float* op = out + 2 + (size_t)row * HWD + f4 * 4;
    float2 v0 = make_float2(sp[0], sp[1]);
    float2 v1 = make_float2(sp[2], sp[3]);
    *(float2*)op = v0; *(float2*)(op + 2) = v1;
}

// fin (2 blocks): [0] contrastive loss -> out[0] | [1] ctc loss -> out[1]
__global__ __launch_bounds__(256) void fin_kernel(
    const float* __restrict__ Sm, const float* __restrict__ scal,
    float* __restrict__ out)
{
    const int blk = blockIdx.x;
    const int t = threadIdx.x;
    if (blk == 1) {
        if (t == 0) out[1] = -(logf(scal[0]) - logf(scal[1]));
        return;
    }
    __shared__ double sa[4], sb2[4], sc[4];
    double A = 0.0, Bv = 0.0, Cv = 0.0;
    for (int c = t; c < CD; c += 256) {
        float tot = 0.f;
        for (int nn = 0; nn < NW; ++nn) {
            float ws = 0.f;
            for (int s = 0; s < NS; ++s) {
                float v = Sm[(nn*NS+s)*CD + c];
                ws += v; Cv += (double)v * v;
            }
            tot += ws; A += (double)ws * ws;
        }
        Bv += (double)tot * tot;
    }
    const int lane = t & 63, w = t >> 6;
    for (int off = 32; off; off >>= 1) {
        A  += __shfl_down(A,  off, 64);
        Bv += __shfl_down(Bv, off, 64);
        Cv += __shfl_down(Cv, off, 64);
    }
    if (lane == 0) { sa[w] = A; sb2[w] = Bv; sc[w] = Cv; }
    __syncthreads();
    if (t == 0) {
        double a = 0, b2 = 0, cc = 0;
        for (int q = 0; q < 4; ++q) { a += sa[q]; b2 += sb2[q]; cc += sc[q]; }
        out[0] = (float)exp(5.0 * (a - cc) / (b2 - a));
    }
}

extern "C" void kernel_launch(void* const* d_in, const int* in_sizes, int n_in,
                              void* d_out, int out_size, void* d_ws, size_t ws_size,
                              hipStream_t stream) {
    const float* lf = (const float*)d_in[0];
    const float* Wc = (const float*)d_in[1];
    const float* bc = (const float*)d_in[2];
    const float* Wq = (const float*)d_in[3];
    const float* bq = (const float*)d_in[4];
    const float* Wk = (const float*)d_in[5];
    const float* bk = (const float*)d_in[6];
    float* out = (float*)d_out;
    float* ws = (float*)d_ws;

    const size_t FEAT = 9216000;
    size_t off = 0;
    auto alloc = [&](size_t nf) { float* p = ws + off; off += (nf + 3) & ~(size_t)3; return p; };
    float* s0     = alloc(FEAT);      // x5T h/l
    float* s1     = alloc(FEAT);      // wT h/l (first 819200 f hold fp32 M2/Weff early)
    float* xwp    = alloc(216000);
    float* seeds  = alloc(16000);
    float* invnl  = alloc(14400);
    float* sumsq  = alloc(14400);
    float* rvsum  = alloc(14400);
    float* cor    = alloc(14400);
    float* proto1 = alloc(3200);
    float* S_img  = alloc(16000);
    float* S_way  = alloc(3200);
    float* S_tot  = alloc(640);
    float* cds    = alloc(14400);
    float* sel    = alloc(14400);
    float* Sm     = alloc(16000);
    float* scal   = alloc(8);
    float* wqtbk  = alloc(640);
    float* bqwk   = alloc(640);
    float* sbb    = alloc(4);
    float* beff   = alloc(640);
    float* wbias  = alloc(640);
    float* WeS    = alloc(409600);    // WeffH/L (2x409600 ushort)
    float* MeS    = alloc(409600);    // M2eH/L

    float* M2   = s1;                 // fp32 temporaries, dead before conv2x writes wT
    float* Weff = s1 + 409600;

    unsigned short* WeH = (unsigned short*)WeS; unsigned short* WeL = WeH + 409600;
    unsigned short* MeH = (unsigned short*)MeS; unsigned short* MeL = MeH + 409600;

    // lfT hi/lo in the pos_index output region; overwritten by post_4 at the end.
    unsigned short* lfTh = (unsigned short*)(out + 2);
    unsigned short* lfTl = lfTh + FEAT;

    unsigned short* s0h = (unsigned short*)s0; unsigned short* s0l = s0h + FEAT;
    unsigned short* s1h = (unsigned short*)s1; unsigned short* s1l = s1h + FEAT;

    prep_a<<<2728, 256, 0, stream>>>(lf, Wc, bc, Wq, bq, Wk, bk,
                                     M2, Weff, wqtbk, bqwk, beff, sbb,
                                     lfTh, lfTl, cor, sumsq, rvsum, proto1, scal, invnl);
    prep_b<<<210, 256, 0, stream>>>(M2, Weff, beff, wqtbk, WeH, WeL, MeH, MeL, wbias);
    conv2x<<<dim3(10,150), 256, 0, stream>>>(lfTh, lfTl, WeH, WeL, MeH, MeL,
                                             beff, wbias, bqwk,
                                             s0h, s0l, s1h, s1l, sumsq, rvsum);
    qk_mega<<<6250, 256, 0, stream>>>(s0h, s0l, s1h, s1l, rvsum, sbb,
                                      lf, invnl, xwp, S_img);
    post_1<<<26, 256, 0, stream>>>(xwp, s0h, s0l, sumsq, S_img, seeds, S_way, S_tot);
    post_2<<<1125, 256, 0, stream>>>(s0h, s0l, sumsq, seeds, lf, invnl,
                                     S_way, S_img, S_tot, cor, cds);
    post_3<<<55, 576, 0, stream>>>(cds, s0h, s0l, cor, sel, proto1);
    post_4<<<13225, 256, 0, stream>>>(lf, invnl, sel, proto1, Sm, scal, out);
    fin_kernel<<<2, 256, 0, stream>>>(Sm, scal, out);
}